// Round 1
// 331.058 us; speedup vs baseline: 1.0116x; 1.0116x over previous
//
#include <hip/hip_runtime.h>
#include <math.h>

#define S_LEN 3072
#define DIM 1536
#define NHEADS 16
#define HDIM 96
#define NPAIR 48

typedef __attribute__((ext_vector_type(8))) _Float16 half8;
typedef __attribute__((ext_vector_type(4))) _Float16 half4v;
typedef __attribute__((ext_vector_type(2))) _Float16 half2v;
typedef __attribute__((ext_vector_type(4))) float f32x4;

__device__ inline void gload16(const void* g, void* l) {
    __builtin_amdgcn_global_load_lds(
        (const __attribute__((address_space(1))) void*)g,
        (__attribute__((address_space(3))) void*)l, 16, 0, 0);
}

// ---------------- prep: fp32 -> fp16 elementwise ----------------
__global__ __launch_bounds__(256)
void convert_f32_f16(const float* __restrict__ src, _Float16* __restrict__ dst, int n4)
{
    int i = blockIdx.x * 256 + threadIdx.x;
    if (i < n4) {
        float4 v = *(const float4*)&src[(size_t)i * 4];
        half4v h = { (_Float16)v.x, (_Float16)v.y, (_Float16)v.z, (_Float16)v.w };
        *(half4v*)&dst[(size_t)i * 4] = h;
    }
}

// ---------------- prep: W[k][n] fp32 -> Wt[n][k] fp16 (64x64 LDS tiles) ----------------
__global__ __launch_bounds__(256)
void transpose_w(const float* __restrict__ w0, const float* __restrict__ w1,
                 const float* __restrict__ w2, const float* __restrict__ w3,
                 _Float16* __restrict__ wt)
{
    __shared__ _Float16 t[64][68];
    const int z = blockIdx.z;
    const float* W = (z == 0) ? w0 : (z == 1) ? w1 : (z == 2) ? w2 : w3;
    _Float16* O = wt + (size_t)z * DIM * DIM;
    const int k0 = blockIdx.y * 64, n0 = blockIdx.x * 64;
    const int tid = threadIdx.x;
    const int r = tid >> 4, c4 = (tid & 15) * 4;
#pragma unroll
    for (int g = 0; g < 4; g++) {
        int kk = r + g * 16;
        float4 v = *(const float4*)&W[(size_t)(k0 + kk) * DIM + n0 + c4];
        t[c4 + 0][kk] = (_Float16)v.x; t[c4 + 1][kk] = (_Float16)v.y;
        t[c4 + 2][kk] = (_Float16)v.z; t[c4 + 3][kk] = (_Float16)v.w;
    }
    __syncthreads();
    const int nr = tid >> 2, ks = (tid & 3) * 16;
#pragma unroll
    for (int s = 0; s < 4; s++)
        *(ushort4*)&O[(size_t)(n0 + nr) * DIM + k0 + ks + s * 4] =
            *(ushort4*)&t[nr][ks + s * 4];
}

// ---------------- fp16 MFMA GEMM with fused RoPE epilogue ----------------
// QKV=true: q,k written [head][s][hd] with RoPE applied; v written TRANSPOSED [head][hd][s].
template<bool QKV>
__global__ __launch_bounds__(256)
void gemm_f16(const _Float16* __restrict__ X,
              const _Float16* __restrict__ W0t, const _Float16* __restrict__ W1t,
              const _Float16* __restrict__ W2t,
              const float* __restrict__ B0, const float* __restrict__ B1,
              const float* __restrict__ B2,
              const float* __restrict__ fc, const float* __restrict__ fs,
              void* __restrict__ outv)
{
    __shared__ __align__(16) _Float16 As[128][64];   // 16 KB
    __shared__ __align__(16) _Float16 Bs[128][64];   // 16 KB

    const int tid = threadIdx.x;
    const int w = tid >> 6, lane = tid & 63;
    const int ln = lane & 15, quad = lane >> 4;
    const int bz = blockIdx.z;
    const _Float16* Wt = W0t; const float* bias = B0;
    if (QKV) { if (bz == 1) { Wt = W1t; bias = B1; } else if (bz == 2) { Wt = W2t; bias = B2; } }
    const int m0 = blockIdx.y * 128, n0 = blockIdx.x * 128;
    const int wm = w >> 1, wn = w & 1;
    const int row8 = lane >> 3, cch = lane & 7;
    const int gch = cch ^ row8;          // swizzled source chunk index

    f32x4 acc[4][4];
#pragma unroll
    for (int i = 0; i < 4; i++)
#pragma unroll
        for (int j = 0; j < 4; j++) acc[i][j] = (f32x4){0.f, 0.f, 0.f, 0.f};

    for (int k0 = 0; k0 < DIM; k0 += 64) {
        __syncthreads();
#pragma unroll
        for (int j = 0; j < 4; j++) {
            const int r = w * 32 + j * 8;
            gload16(X  + (size_t)(m0 + r + row8) * DIM + k0 + gch * 8, &As[r][0]);
            gload16(Wt + (size_t)(n0 + r + row8) * DIM + k0 + gch * 8, &Bs[r][0]);
        }
        __syncthreads();

        half8 a[4][2], b[4][2];
#pragma unroll
        for (int mt = 0; mt < 4; mt++) {
            int m = wm * 64 + mt * 16 + ln;
#pragma unroll
            for (int ks = 0; ks < 2; ks++) {
                int s = (ks * 4 + quad) ^ (ln & 7);
                a[mt][ks] = *(const half8*)&As[m][s * 8];
            }
        }
#pragma unroll
        for (int nt = 0; nt < 4; nt++) {
            int n = wn * 64 + nt * 16 + ln;
#pragma unroll
            for (int ks = 0; ks < 2; ks++) {
                int s = (ks * 4 + quad) ^ (ln & 7);
                b[nt][ks] = *(const half8*)&Bs[n][s * 8];
            }
        }
#pragma unroll
        for (int ks = 0; ks < 2; ks++)
#pragma unroll
            for (int mt = 0; mt < 4; mt++)
#pragma unroll
                for (int nt = 0; nt < 4; nt++)
                    acc[mt][nt] = __builtin_amdgcn_mfma_f32_16x16x32_f16(
                        a[mt][ks], b[nt][ks], acc[mt][nt], 0, 0, 0);
    }

    // epilogue: C/D 16x16 layout col=ln, row=quad*4+reg
#pragma unroll
    for (int nt = 0; nt < 4; nt++) {
        int col = n0 + wn * 64 + nt * 16 + ln;
        float bv = bias[col];
        int head = col / HDIM, hd = col % HDIM;
        int jc = hd >> 1;                   // pair index; parity of hd == parity of ln
        bool isreal = (ln & 1) == 0;
#pragma unroll
        for (int mt = 0; mt < 4; mt++) {
            int row0 = m0 + wm * 64 + mt * 16 + quad * 4;
            if (QKV && bz == 2) {
                // V^T [head][hd][s]: 4 consecutive s values -> packed 8B store
                half4v p;
#pragma unroll
                for (int r = 0; r < 4; r++) p[r] = (_Float16)(acc[mt][nt][r] + bv);
                *(half4v*)&((_Float16*)outv)[(((size_t)2 * NHEADS + head) * HDIM + hd) * S_LEN + row0] = p;
            } else if (QKV) {
                // q/k with fused RoPE: pair partner lives in lane^1
                float v[4], vp[4];
#pragma unroll
                for (int r = 0; r < 4; r++) v[r] = acc[mt][nt][r] + bv;
#pragma unroll
                for (int r = 0; r < 4; r++) vp[r] = __shfl_xor(v[r], 1);
#pragma unroll
                for (int r = 0; r < 4; r++) {
                    int srow = row0 + r;
                    int pos = (jc < 32) ? (srow >> 6) : (srow & 63);
                    float c  = fc[pos * NPAIR + jc];
                    float sn = fs[pos * NPAIR + jc];
                    float xr = isreal ? v[r] : vp[r];
                    float xi = isreal ? vp[r] : v[r];
                    float rot = isreal ? (xr * c - xi * sn) : (xr * sn + xi * c);
                    float outval = (jc < 16) ? v[r] : rot;
                    ((_Float16*)outv)[(((size_t)bz * NHEADS + head) * S_LEN + srow) * HDIM + hd]
                        = (_Float16)outval;
                }
            } else {
#pragma unroll
                for (int r = 0; r < 4; r++)
                    ((float*)outv)[(size_t)(row0 + r) * DIM + col] = acc[mt][nt][r] + bv;
            }
        }
    }
}

// ---------------- MFMA fp16 flash attention, in-block KV-split ----------------
// 256 threads / 4 waves. Wave-pair p = wid>>1 owns KV half p (24 tiles) with its own
// Ks/Vt buffers; pairs merge (m,l,O) through LDS at the end. This triples resident
// waves/CU (6 -> 12) vs the old 2-wave/768-block layout, which rocprof showed was
// occupancy/latency-bound (MfmaUtil 18%, VALUBusy 32%, Occupancy 14%, no pipe >35%).
// PV uses mfma_f32_16x16x16f16: its B-frag (col=ln, k=quad*4+j) IS the QK C-layout
// (col=ln, row=quad*4+r), so P repacks in-lane -> the Pl LDS round-trip is gone and
// LDS fits 3 blocks/CU (3 x 54272 = 162816 <= 163840).
// Softmax in log2 domain (log2e folded into Q scale); defer-max (THR=8 in log2) skips
// cross-quad shfls + rescale on most tiles; l cross-quad reduce deferred to epilogue.
// Prefetch in NAMED uint4 scalars + sched_barrier(0) pins the loads early (the old
// kernel's VGPR=104 proved the compiler had sunk the "prefetch" to its commit point).
__global__ __launch_bounds__(256, 3)
void attn_mfma_kernel(const _Float16* __restrict__ qh, const _Float16* __restrict__ kh,
                      const _Float16* __restrict__ vtg, _Float16* __restrict__ aoh)
{
    __shared__ __align__(16) _Float16 Ks[2][64][104];  // 26.0 KB, stride 208B (bank-balanced)
    __shared__ __align__(16) _Float16 Vt[2][96][72];   // 27.0 KB, stride 144B + XOR chunk swizzle

    const int tid  = threadIdx.x;      // 0..255
    const int wid  = tid >> 6;         // 0..3
    const int p    = wid >> 1;         // KV half this wave-pair owns
    const int wp   = wid & 1;          // wave within pair
    const int lane = tid & 63;
    const int ln   = lane & 15;
    const int quad = lane >> 4;
    const int h    = blockIdx.y;
    const int q0   = blockIdx.x * 64;
    const float scale_ = 0.10206207261596577f * 1.4426950408889634f;  // 1/sqrt(96) * log2(e)
    const int NT = (S_LEN / 2) / 64;   // 24 tiles per pair

    // Q fragments for 2 q-blocks (B-operand: col=ln=qrow, k=quad*8+j); both pairs load
    // the same 64 q-rows of this block.
    half8 aq[2][3];
#pragma unroll
    for (int qs = 0; qs < 2; qs++) {
        const _Float16* qrow = qh + (((size_t)h * S_LEN) + q0 + (wp * 2 + qs) * 16 + ln) * HDIM;
#pragma unroll
        for (int kb = 0; kb < 3; kb++) {
            half8 a = *(const half8*)&qrow[kb * 32 + quad * 8];
            half8 v;
#pragma unroll
            for (int i = 0; i < 8; i++) v[i] = (_Float16)((float)a[i] * scale_);
            aq[qs][kb] = v;
        }
    }

    f32x4 o[2][6];
#pragma unroll
    for (int qs = 0; qs < 2; qs++)
#pragma unroll
        for (int dn = 0; dn < 6; dn++) o[qs][dn] = (f32x4){0.f, 0.f, 0.f, 0.f};
    float m_[2] = {-INFINITY, -INFINITY}, l_[2] = {0.f, 0.f};  // l_ is per-lane (quad-partial)

    const _Float16* kbase = kh + ((size_t)h * S_LEN + p * (S_LEN / 2)) * HDIM;
    const _Float16* vbase = vtg + (size_t)h * HDIM * S_LEN + p * (S_LEN / 2);

    // staging assignments are pair-local (128 threads per pair)
    const int tp = tid & 127;
    const int krow = tp >> 1, kc0 = (tp & 1) * 6;
    const _Float16* ksrc0 = kbase + (size_t)krow * HDIM + kc0 * 8;
    _Float16* kdst = &Ks[p][krow][kc0 * 8];
    const int vd0 = tp >> 3, vc = tp & 7;
    const _Float16* vsrc0 = vbase + (size_t)vd0 * S_LEN + vc * 8;
    _Float16* vdst = &Vt[p][vd0][(vc ^ (vd0 & 7)) * 8];

    // prefetch tile 0 (named scalars -> guaranteed SSA/registers)
    uint4 kp0, kp1, kp2, kp3, kp4, kp5, vp0, vp1, vp2, vp3, vp4, vp5;
    kp0 = *(const uint4*)(ksrc0 + 0 * 8);  kp1 = *(const uint4*)(ksrc0 + 1 * 8);
    kp2 = *(const uint4*)(ksrc0 + 2 * 8);  kp3 = *(const uint4*)(ksrc0 + 3 * 8);
    kp4 = *(const uint4*)(ksrc0 + 4 * 8);  kp5 = *(const uint4*)(ksrc0 + 5 * 8);
    vp0 = *(const uint4*)(vsrc0 + 0 * 16 * S_LEN);
    vp1 = *(const uint4*)(vsrc0 + 1 * 16 * S_LEN);
    vp2 = *(const uint4*)(vsrc0 + 2 * 16 * S_LEN);
    vp3 = *(const uint4*)(vsrc0 + 3 * 16 * S_LEN);
    vp4 = *(const uint4*)(vsrc0 + 4 * 16 * S_LEN);
    vp5 = *(const uint4*)(vsrc0 + 5 * 16 * S_LEN);

    for (int kt = 0; kt < NT; ++kt) {
        __syncthreads();   // previous tile's LDS reads complete (both pairs in lockstep)
        // commit prefetched tile to this pair's LDS buffers
        *(uint4*)(kdst + 0 * 8) = kp0;  *(uint4*)(kdst + 1 * 8) = kp1;
        *(uint4*)(kdst + 2 * 8) = kp2;  *(uint4*)(kdst + 3 * 8) = kp3;
        *(uint4*)(kdst + 4 * 8) = kp4;  *(uint4*)(kdst + 5 * 8) = kp5;
        *(uint4*)(vdst + 0 * 16 * 72) = vp0;  *(uint4*)(vdst + 1 * 16 * 72) = vp1;
        *(uint4*)(vdst + 2 * 16 * 72) = vp2;  *(uint4*)(vdst + 3 * 16 * 72) = vp3;
        *(uint4*)(vdst + 4 * 16 * 72) = vp4;  *(uint4*)(vdst + 5 * 16 * 72) = vp5;
        __syncthreads();

        // issue next tile's K loads NOW; sched_barrier pins them before the compute
        if (kt + 1 < NT) {
            const _Float16* ks2 = ksrc0 + (size_t)(kt + 1) * 64 * HDIM;
            kp0 = *(const uint4*)(ks2 + 0 * 8);  kp1 = *(const uint4*)(ks2 + 1 * 8);
            kp2 = *(const uint4*)(ks2 + 2 * 8);  kp3 = *(const uint4*)(ks2 + 3 * 8);
            kp4 = *(const uint4*)(ks2 + 4 * 8);  kp5 = *(const uint4*)(ks2 + 5 * 8);
            __builtin_amdgcn_sched_barrier(0);
        }

        // S^T = K * Q^T; K-frags read ONCE, used for both q-blocks
        f32x4 s[2][4];
#pragma unroll
        for (int nb = 0; nb < 4; nb++) {
            half8 ak0 = *(const half8*)&Ks[p][nb * 16 + ln][0 * 32 + quad * 8];
            half8 ak1 = *(const half8*)&Ks[p][nb * 16 + ln][1 * 32 + quad * 8];
            half8 ak2 = *(const half8*)&Ks[p][nb * 16 + ln][2 * 32 + quad * 8];
#pragma unroll
            for (int qs = 0; qs < 2; qs++) {
                f32x4 acc = (f32x4){0.f, 0.f, 0.f, 0.f};
                acc = __builtin_amdgcn_mfma_f32_16x16x32_f16(ak0, aq[qs][0], acc, 0, 0, 0);
                acc = __builtin_amdgcn_mfma_f32_16x16x32_f16(ak1, aq[qs][1], acc, 0, 0, 0);
                acc = __builtin_amdgcn_mfma_f32_16x16x32_f16(ak2, aq[qs][2], acc, 0, 0, 0);
                s[qs][nb] = acc;
            }
        }

        // online softmax in log2 domain; defer-max skips all cross-lane work most tiles
        half4v ap[2][4];
#pragma unroll
        for (int qs = 0; qs < 2; qs++) {
            float ma = fmaxf(fmaxf(s[qs][0][0], s[qs][0][1]), fmaxf(s[qs][0][2], s[qs][0][3]));
            float mb = fmaxf(fmaxf(s[qs][1][0], s[qs][1][1]), fmaxf(s[qs][1][2], s[qs][1][3]));
            float mc = fmaxf(fmaxf(s[qs][2][0], s[qs][2][1]), fmaxf(s[qs][2][2], s[qs][2][3]));
            float md = fmaxf(fmaxf(s[qs][3][0], s[qs][3][1]), fmaxf(s[qs][3][2], s[qs][3][3]));
            float mx = fmaxf(fmaxf(ma, mb), fmaxf(mc, md));
            if (!__all(mx <= m_[qs] + 8.0f)) {       // rescale only when max really grew
                mx = fmaxf(mx, __shfl_xor(mx, 16));
                mx = fmaxf(mx, __shfl_xor(mx, 32));
                float mn = fmaxf(m_[qs], mx);
                float al = __builtin_amdgcn_exp2f(m_[qs] - mn);
                m_[qs] = mn;
                l_[qs] *= al;
#pragma unroll
                for (int dn = 0; dn < 6; dn++)
#pragma unroll
                    for (int r = 0; r < 4; r++) o[qs][dn][r] *= al;
            }
            float rs = 0.f;
            float mq = m_[qs];
#pragma unroll
            for (int nb = 0; nb < 4; nb++) {
                float p0 = __builtin_amdgcn_exp2f(s[qs][nb][0] - mq);
                float p1 = __builtin_amdgcn_exp2f(s[qs][nb][1] - mq);
                float p2 = __builtin_amdgcn_exp2f(s[qs][nb][2] - mq);
                float p3 = __builtin_amdgcn_exp2f(s[qs][nb][3] - mq);
                rs += (p0 + p1) + (p2 + p3);
                half4v pk = { (_Float16)p0, (_Float16)p1, (_Float16)p2, (_Float16)p3 };
                ap[qs][nb] = pk;                      // B-frag of 16x16x16: col=ln, k=quad*4+j
            }
            l_[qs] += rs;                             // cross-quad reduce deferred to epilogue
        }

        // issue next tile's V loads; PV hides their latency
        if (kt + 1 < NT) {
            const _Float16* vs2 = vsrc0 + (kt + 1) * 64;
            vp0 = *(const uint4*)(vs2 + 0 * 16 * S_LEN);
            vp1 = *(const uint4*)(vs2 + 1 * 16 * S_LEN);
            vp2 = *(const uint4*)(vs2 + 2 * 16 * S_LEN);
            vp3 = *(const uint4*)(vs2 + 3 * 16 * S_LEN);
            vp4 = *(const uint4*)(vs2 + 4 * 16 * S_LEN);
            vp5 = *(const uint4*)(vs2 + 5 * 16 * S_LEN);
            __builtin_amdgcn_sched_barrier(0);
        }

        // PV with 16x16x16: A = V^T frag (row=ln -> d, k=quad*4+j -> kv), B = ap (in-reg P)
#pragma unroll
        for (int nb = 0; nb < 4; nb++) {
            const int off = (((nb * 2 + (quad >> 1)) ^ (ln & 7)) * 8) + (quad & 1) * 4;
#pragma unroll
            for (int dn = 0; dn < 6; dn++) {
                half4v av = *(const half4v*)&Vt[p][dn * 16 + ln][off];
                o[0][dn] = __builtin_amdgcn_mfma_f32_16x16x16f16(av, ap[0][nb], o[0][dn], 0, 0, 0);
                o[1][dn] = __builtin_amdgcn_mfma_f32_16x16x16f16(av, ap[1][nb], o[1][dn], 0, 0, 0);
            }
        }
    }

    // ---- cross-pair merge through LDS ----
    __syncthreads();                       // all LDS reads of the last tiles complete
    float lt[2];
#pragma unroll
    for (int qs = 0; qs < 2; qs++) {       // finish the deferred cross-quad l reduction
        float l = l_[qs];
        l += __shfl_xor(l, 16);
        l += __shfl_xor(l, 32);
        lt[qs] = l;
    }
    float*  scr = (float*)&Ks[0][0][0];    // 64 x 100 f32 partial-O (25.6 KB, fits Ks region)
    float2* mlb = (float2*)&Vt[0][0][0];   // 64 x {m,l} (512 B)
    if (p == 1) {
#pragma unroll
        for (int qs = 0; qs < 2; qs++) {
            int row = (wp * 2 + qs) * 16 + ln;
            if (quad == 0) mlb[row] = make_float2(m_[qs], lt[qs]);
#pragma unroll
            for (int dn = 0; dn < 6; dn++)
                *(f32x4*)&scr[row * 100 + dn * 16 + quad * 4] = o[qs][dn];
        }
    }
    __syncthreads();
    if (p == 0) {
#pragma unroll
        for (int qs = 0; qs < 2; qs++) {
            int row = (wp * 2 + qs) * 16 + ln;
            float2 ml1 = mlb[row];
            float mm = fmaxf(m_[qs], ml1.x);
            float a0 = __builtin_amdgcn_exp2f(m_[qs] - mm);
            float a1 = __builtin_amdgcn_exp2f(ml1.x - mm);
            float li = 1.0f / (lt[qs] * a0 + ml1.y * a1);
            const size_t rowbase = (size_t)(q0 + row) * DIM + h * HDIM;
#pragma unroll
            for (int dn = 0; dn < 6; dn++) {
                f32x4 o1 = *(const f32x4*)&scr[row * 100 + dn * 16 + quad * 4];
                half4v pk;
#pragma unroll
                for (int r = 0; r < 4; r++)
                    pk[r] = (_Float16)((o[qs][dn][r] * a0 + o1[r] * a1) * li);
                *(half4v*)&aoh[rowbase + dn * 16 + quad * 4] = pk;
            }
        }
    }
}

extern "C" void kernel_launch(void* const* d_in, const int* in_sizes, int n_in,
                              void* d_out, int out_size, void* d_ws, size_t ws_size,
                              hipStream_t stream) {
    const float* x  = (const float*)d_in[0];
    const float* wq = (const float*)d_in[1];
    const float* bq = (const float*)d_in[2];
    const float* wk = (const float*)d_in[3];
    const float* bk = (const float*)d_in[4];
    const float* wv = (const float*)d_in[5];
    const float* bv = (const float*)d_in[6];
    const float* wo = (const float*)d_in[7];
    const float* bo = (const float*)d_in[8];
    const float* fc = (const float*)d_in[9];
    const float* fs = (const float*)d_in[10];
    float* out = (float*)d_out;

    const size_t per  = (size_t)NHEADS * S_LEN * HDIM;   // 4,718,592
    const size_t dim2 = (size_t)DIM * DIM;               // 2,359,296
    _Float16* hws  = (_Float16*)d_ws;
    _Float16* qkvh = hws;                 // q,k fp16 [head][s][hd] (roped); v fp16 [head][hd][s]
    _Float16* qh   = qkvh;
    _Float16* kh   = qkvh + per;
    _Float16* vth  = qkvh + 2 * per;
    _Float16* xh   = hws + 3 * per;       // x fp16; later reused as ao fp16
    _Float16* wth  = hws + 4 * per;       // 4 transposed weights fp16

    convert_f32_f16<<<(int)((S_LEN * DIM / 4 + 255) / 256), 256, 0, stream>>>(
        x, xh, S_LEN * DIM / 4);
    transpose_w<<<dim3(DIM / 64, DIM / 64, 4), 256, 0, stream>>>(wq, wk, wv, wo, wth);

    // fused QKV projection + RoPE -> fp16
    gemm_f16<true><<<dim3(DIM / 128, S_LEN / 128, 3), 256, 0, stream>>>(
        xh, wth, wth + dim2, wth + 2 * dim2, bq, bk, bv, fc, fs, qkvh);
    attn_mfma_kernel<<<dim3(S_LEN / 64, NHEADS), 256, 0, stream>>>(qh, kh, vth, xh);
    gemm_f16<false><<<dim3(DIM / 128, S_LEN / 128, 1), 256, 0, stream>>>(
        xh, wth + 3 * dim2, nullptr, nullptr, bo, nullptr, nullptr, fc, fs, out);
}